// Round 9
// baseline (201.274 us; speedup 1.0000x reference)
//
#include <hip/hip_runtime.h>
#include <hip/hip_bf16.h>
#include <cstdint>
#include <cstddef>

// ---------- types ----------
typedef __attribute__((ext_vector_type(8))) _Float16 half8;
typedef __attribute__((ext_vector_type(4))) _Float16 half4v;
typedef __attribute__((ext_vector_type(4))) float floatx4;

#define MFMA16(a, b, c) __builtin_amdgcn_mfma_f32_16x16x32_f16((a), (b), (c), 0, 0, 0)

// direct global->LDS DMA, 16B per lane, dest = uniform base + lane*16
#define GLOAD_LDS16(g, l)                                                     \
    __builtin_amdgcn_global_load_lds(                                         \
        (const __attribute__((address_space(1))) void*)(g),                   \
        (__attribute__((address_space(3))) void*)(l), 16, 0, 0)

// Problem constants: A=64, T=512, D=256, H=4, HD=64
#define NFEAT 8388608   // 64*512*256
#define NW    65536     // 256*256
#define NCVT  8448      // convert blocks; mask blocks appended after

// ---------- fp32 -> fp16 convert + geometry-mask precompute ----------
__global__ __launch_bounds__(256) void convert_kernel(
    const float* __restrict__ feat, const float* __restrict__ wq,
    const float* __restrict__ wk, const float* __restrict__ wv,
    const float* __restrict__ wo, const float* __restrict__ positions,
    const int* __restrict__ mdp, const int* __restrict__ twp,
    _Float16* __restrict__ out, uint64_t* __restrict__ maskbuf)
{
    if (blockIdx.x >= NCVT) {
        const int n2 = blockIdx.x - NCVT;       // 0..511
        const int a = n2 >> 3, qt = n2 & 7;
        const int q0 = qt * 64, s_base = q0 - 64;
        const int tid = threadIdx.x, lane = tid & 63, wid = tid >> 6;
        const int quad = lane >> 4, l16 = lane & 15;
        const size_t abase = (size_t)a * 512;
        const int md = *mdp, tw = *twp;
        const float md2 = (float)(md * md);

        float qpx[4], qpy[4];
        int trow[4];
#pragma unroll
        for (int r = 0; r < 4; ++r) {
            int m = wid * 16 + quad * 4 + r;
            trow[r] = q0 + m;
            float2 qp = *(const float2*)(positions + (abase + q0 + m) * 2);
            qpx[r] = qp.x;
            qpy[r] = qp.y;
        }
        uint64_t ok_bits = 0;
#pragma unroll
        for (int j = 0; j < 12; ++j) {
            int si = j * 16 + l16;
            int sr = s_base + si;
            int sc = min(max(sr, 0), 511);
            float2 kp = *(const float2*)(positions + (abase + sc) * 2);
            bool svalid = (sr >= 0) && (sr < 512);
#pragma unroll
            for (int r = 0; r < 4; ++r) {
                float dx = qpx[r] - kp.x, dy = qpy[r] - kp.y;
                float d2 = dx * dx + dy * dy;
                int dt = trow[r] - sr; dt = dt < 0 ? -dt : dt;
                if (svalid && (d2 <= md2) && (dt <= tw))
                    ok_bits |= (1ull << (j * 4 + r));
            }
        }
        maskbuf[(size_t)n2 * 256 + tid] = ok_bits;
        return;
    }

    long tid  = (long)blockIdx.x * blockDim.x + threadIdx.x;
    long base = tid * 4;
    const float* src;
    long off;
    if (base < NFEAT) { src = feat; off = base; }
    else {
        long r = base - NFEAT;
        int  w = (int)(r >> 16);
        off = r & (NW - 1);
        src = (w == 0) ? wq : (w == 1) ? wk : (w == 2) ? wv : wo;
    }
    float4 v = *(const float4*)(src + off);
    half4v h = { (_Float16)v.x, (_Float16)v.y, (_Float16)v.z, (_Float16)v.w };
    *(half4v*)(out + base) = h;
}

// ---------- fused QKV GEMM: X LDS-resident, W fragments DIRECT from global ----
// NT-MFMA B-frag rows are natural W rows -> no W LDS, no W barriers. One
// barrier total (X DMA). 1D grid 512: xcd = n&7; per XCD 32 bm x 2 bn.
__global__ __launch_bounds__(256) void qkv_fused(
    const _Float16* __restrict__ featH, const _Float16* __restrict__ WH,
    const float* __restrict__ bq, const float* __restrict__ bk,
    const float* __restrict__ bv,
    _Float16* __restrict__ Qb, _Float16* __restrict__ Kb, _Float16* __restrict__ Vb)
{
    __shared__ _Float16 Xs[4 * 128 * 64];   // 64 KB slab-major, XOR swizzle

    const int n   = blockIdx.x;
    const int idx = n >> 3;
    const int bm  = (n & 7) * 32 + (idx >> 1);
    const int bn  = idx & 1;

    const int tid  = threadIdx.x;
    const int lane = tid & 63, wid = tid >> 6;
    const int quad = lane >> 4, l16 = lane & 15;
    const int wm = wid & 1, wn = wid >> 1;

    // ---- stage X once via DMA: 4 slabs of 64 cols, XOR swizzle ----
    const _Float16* Xg = featH + (size_t)bm * 128 * 256;
#pragma unroll
    for (int sl = 0; sl < 4; ++sl)
#pragma unroll
        for (int i = 0; i < 4; ++i) {
            int grp = wid * 4 + i;
            int row = grp * 8 + (lane >> 3);
            int sc  = (lane & 7) ^ (row & 7);
            GLOAD_LDS16(Xg + (size_t)row * 256 + sl * 64 + sc * 8,
                        Xs + sl * 8192 + grp * 512);
        }
    __syncthreads();   // the only barrier

    const float* bz[3] = { bq, bk, bv };
    _Float16*    oz[3] = { Qb, Kb, Vb };

#pragma unroll 1
    for (int z = 0; z < 3; ++z) {
        const _Float16* Wb = WH + (size_t)z * NW + (size_t)bn * 32768
                           + (size_t)(wn * 64 + l16) * 256 + quad * 8;
        floatx4 acc[4][4] = {};
#pragma unroll
        for (int ks = 0; ks < 4; ++ks)
#pragma unroll
            for (int kh = 0; kh < 2; ++kh) {
                half8 af[4], bf[4];
#pragma unroll
                for (int ni = 0; ni < 4; ++ni)
                    bf[ni] = *(const half8*)(Wb + (size_t)ni * 16 * 256
                                             + ks * 64 + kh * 32);
#pragma unroll
                for (int mi = 0; mi < 4; ++mi) {
                    int row = wm * 64 + mi * 16 + l16;
                    int cs  = (kh * 4 + quad) ^ (row & 7);
                    af[mi] = *(const half8*)(&Xs[ks * 8192 + row * 64 + cs * 8]);
                }
#pragma unroll
                for (int mi = 0; mi < 4; ++mi)
#pragma unroll
                    for (int ni = 0; ni < 4; ++ni)
                        acc[mi][ni] = MFMA16(af[mi], bf[ni], acc[mi][ni]);
            }

        // epilogue z: C/D layout col = lane&15, row = quad*4 + r
        const float* bias = bz[z];
        _Float16*    outp = oz[z];
#pragma unroll
        for (int ni = 0; ni < 4; ++ni) {
            int col = bn * 128 + wn * 64 + ni * 16 + l16;
            float bv2 = bias[col];
#pragma unroll
            for (int mi = 0; mi < 4; ++mi)
#pragma unroll
                for (int r = 0; r < 4; ++r) {
                    int row = bm * 128 + wm * 64 + mi * 16 + quad * 4 + r;
                    outp[(size_t)row * 256 + col] =
                        (_Float16)(acc[mi][ni][r] + bv2);
                }
        }
    }
}

// ---------- banded sparse attention: K DIRECT from global, one barrier ------
// LDS: Vt 24 KB + per-wave P chunk 4x1.25 KB = 29 KB -> 5 blocks/CU (LDS).
// 1D grid 2048: xcd = n&7; per XCD 8 animals x (8 qt x 4 h), h fastest.
__global__ __launch_bounds__(256) void attn_kernel(
    const _Float16* __restrict__ Qb, const _Float16* __restrict__ Kb,
    const _Float16* __restrict__ Vb, const uint64_t* __restrict__ maskbuf,
    _Float16* __restrict__ attnb)
{
    const int n   = blockIdx.x;
    const int idx = n >> 3;
    const int a   = (n & 7) * 8 + (idx >> 5);
    const int rem = idx & 31;
    const int qt  = rem >> 2, h = rem & 3;

    const int q0 = qt * 64;
    const int s_base = q0 - 64;
    const int tid = threadIdx.x, lane = tid & 63, wid = tid >> 6;
    const int quad = lane >> 4, l16 = lane & 15;

    __shared__ _Float16 Vt[64 * 192];     // packed V^T (XOR chunk swizzle)
    __shared__ _Float16 Pbuf[4 * 16 * 40];// per-wave P chunk, stride 40

    const size_t abase = (size_t)a * 512;
    const uint64_t ok_bits = maskbuf[(size_t)(a * 8 + qt) * 256 + tid];

    const size_t qrow = abase + q0 + wid * 16 + l16;
    half8 aq0 = *(const half8*)(Qb + qrow * 256 + h * 64 + quad * 8);
    half8 aq1 = *(const half8*)(Qb + qrow * 256 + h * 64 + 32 + quad * 8);

    // ---- stage V^T packed [64][192], XOR chunk swizzle, paired b32 writes ----
#pragma unroll
    for (int i = 0; i < 3; ++i) {
        int g   = tid + 256 * i;
        int si2 = (g % 96) * 2;
        int d0  = (g / 96) * 8;
        int sa  = min(max(s_base + si2, 0), 511);
        int sb  = min(max(s_base + si2 + 1, 0), 511);
        half8 v0 = *(const half8*)(Vb + (abase + sa) * 256 + h * 64 + d0);
        half8 v1 = *(const half8*)(Vb + (abase + sb) * 256 + h * 64 + d0);
        int c = si2 >> 3;
#pragma unroll
        for (int j = 0; j < 8; ++j) {
            int d  = d0 + j;
            int cs = (c & ~7) | ((c & 7) ^ (d & 7));
            union { _Float16 hh[2]; uint32_t u; } p;
            p.hh[0] = v0[j]; p.hh[1] = v1[j];
            *(uint32_t*)(&Vt[d * 192 + cs * 8 + (si2 & 7)]) = p.u;
        }
    }
    __syncthreads();   // the only barrier (Vt visible)

    // ---- S = Q K^T: K B-frags loaded DIRECT from global (natural K rows) ----
    floatx4 S[12];
#pragma unroll
    for (int j = 0; j < 12; ++j) {
        int si = j * 16 + l16;
        int sc = min(max(s_base + si, 0), 511);
        const _Float16* kp = Kb + (abase + sc) * 256 + h * 64 + quad * 8;
        half8 bk0 = *(const half8*)(kp);
        half8 bk1 = *(const half8*)(kp + 32);
        floatx4 acc = {};
        acc = MFMA16(aq0, bk0, acc);
        acc = MFMA16(aq1, bk1, acc);
#pragma unroll
        for (int r = 0; r < 4; ++r) {
            bool ok = (ok_bits >> (j * 4 + r)) & 1;
            S[j][r] = __expf(ok ? acc[r] * 0.125f : -1e30f);
        }
    }

    // ---- row sums (quad shuffles); diagonal always allowed -> l > 0 ----
    float minv[4];
#pragma unroll
    for (int r = 0; r < 4; ++r) {
        float l = 0.f;
#pragma unroll
        for (int j = 0; j < 12; ++j) l += S[j][r];
        l += __shfl_xor(l, 1);
        l += __shfl_xor(l, 2);
        l += __shfl_xor(l, 4);
        l += __shfl_xor(l, 8);
        minv[r] = 1.0f / l;
    }

    // ---- PV, chunked through per-wave P buffer (same-wave RAW: lgkmcnt only,
    //      no barrier). P stride 40 halfs -> 2-way max bank aliasing. ----
    _Float16* P = Pbuf + wid * (16 * 40);
    floatx4 accO[4] = {};
#pragma unroll
    for (int k = 0; k < 6; ++k) {
#pragma unroll
        for (int jj = 0; jj < 2; ++jj) {
            int j = 2 * k + jj;
#pragma unroll
            for (int r = 0; r < 4; ++r)
                P[(quad * 4 + r) * 40 + jj * 16 + l16] =
                    (_Float16)(S[j][r] * minv[r]);
        }
        half8 af = *(const half8*)(&P[l16 * 40 + quad * 8]);
#pragma unroll
        for (int nn = 0; nn < 4; ++nn) {
            int row = nn * 16 + l16;
            int c   = k * 4 + quad;
            int cs  = (c & ~7) | ((c & 7) ^ (row & 7));
            half8 bv = *(const half8*)(&Vt[row * 192 + cs * 8]);
            accO[nn] = MFMA16(af, bv, accO[nn]);
        }
    }

#pragma unroll
    for (int nn = 0; nn < 4; ++nn)
#pragma unroll
        for (int r = 0; r < 4; ++r) {
            int row = q0 + wid * 16 + quad * 4 + r;
            attnb[(abase + row) * 256 + h * 64 + nn * 16 + l16] =
                (_Float16)accO[nn][r];
        }
}

// ---------- out GEMM: A LDS via DMA, Wo fragments direct from global --------
__global__ __launch_bounds__(256) void out_gemm(
    const _Float16* __restrict__ attnH, const _Float16* __restrict__ WoH,
    const float* __restrict__ bo, float* __restrict__ out)
{
    __shared__ _Float16 Xs[4 * 128 * 64];   // 64 KB slab-major

    const int n   = blockIdx.x;
    const int idx = n >> 3;
    const int bm  = (n & 7) * 32 + (idx >> 1);
    const int bn  = idx & 1;

    const int tid  = threadIdx.x;
    const int lane = tid & 63, wid = tid >> 6;
    const int quad = lane >> 4, l16 = lane & 15;
    const int wm = wid & 1, wn = wid >> 1;

    const _Float16* Ag = attnH + (size_t)bm * 128 * 256;
#pragma unroll
    for (int sl = 0; sl < 4; ++sl)
#pragma unroll
        for (int i = 0; i < 4; ++i) {
            int grp = wid * 4 + i;
            int row = grp * 8 + (lane >> 3);
            int sc  = (lane & 7) ^ (row & 7);
            GLOAD_LDS16(Ag + (size_t)row * 256 + sl * 64 + sc * 8,
                        Xs + sl * 8192 + grp * 512);
        }
    __syncthreads();   // the only barrier

    const _Float16* Wb = WoH + (size_t)bn * 32768
                       + (size_t)(wn * 64 + l16) * 256 + quad * 8;
    floatx4 acc[4][4] = {};
#pragma unroll
    for (int ks = 0; ks < 4; ++ks)
#pragma unroll
        for (int kh = 0; kh < 2; ++kh) {
            half8 af[4], bf[4];
#pragma unroll
            for (int ni = 0; ni < 4; ++ni)
                bf[ni] = *(const half8*)(Wb + (size_t)ni * 16 * 256
                                         + ks * 64 + kh * 32);
#pragma unroll
            for (int mi = 0; mi < 4; ++mi) {
                int row = wm * 64 + mi * 16 + l16;
                int cs  = (kh * 4 + quad) ^ (row & 7);
                af[mi] = *(const half8*)(&Xs[ks * 8192 + row * 64 + cs * 8]);
            }
#pragma unroll
            for (int mi = 0; mi < 4; ++mi)
#pragma unroll
                for (int ni = 0; ni < 4; ++ni)
                    acc[mi][ni] = MFMA16(af[mi], bf[ni], acc[mi][ni]);
        }

#pragma unroll
    for (int ni = 0; ni < 4; ++ni) {
        int col = bn * 128 + wn * 64 + ni * 16 + l16;
        float bv = bo[col];
#pragma unroll
        for (int mi = 0; mi < 4; ++mi)
#pragma unroll
            for (int r = 0; r < 4; ++r) {
                int row = bm * 128 + wm * 64 + mi * 16 + quad * 4 + r;
                out[(size_t)row * 256 + col] = acc[mi][ni][r] + bv;
            }
    }
}

// ---------- launch ----------
extern "C" void kernel_launch(void* const* d_in, const int* in_sizes, int n_in,
                              void* d_out, int out_size, void* d_ws, size_t ws_size,
                              hipStream_t stream)
{
    const float* feat = (const float*)d_in[0];
    const float* pos  = (const float*)d_in[1];
    const float* Wq   = (const float*)d_in[2];
    const float* bq   = (const float*)d_in[3];
    const float* Wk   = (const float*)d_in[4];
    const float* bk   = (const float*)d_in[5];
    const float* Wv   = (const float*)d_in[6];
    const float* bv   = (const float*)d_in[7];
    const float* Wo   = (const float*)d_in[8];
    const float* bo   = (const float*)d_in[9];
    const int*   md   = (const int*)d_in[10];
    const int*   tw   = (const int*)d_in[11];
    float*       out  = (float*)d_out;

    _Float16* ws    = (_Float16*)d_ws;
    _Float16* featH = ws;                      // NFEAT
    _Float16* WH    = featH + NFEAT;           // 4*NW: WqH, WkH, WvH, WoH
    _Float16* WoHp  = WH + 3 * (size_t)NW;
    _Float16* Qb    = WH + 4 * (size_t)NW;
    _Float16* Kb    = Qb + NFEAT;
    _Float16* Vb    = Kb + NFEAT;
    _Float16* attnH = Vb + NFEAT;
    uint64_t* maskb = (uint64_t*)(attnH + NFEAT);   // 1 MB

    convert_kernel<<<NCVT + 512, 256, 0, stream>>>(
        feat, Wq, Wk, Wv, Wo, pos, md, tw, ws, maskb);

    qkv_fused<<<512, 256, 0, stream>>>(featH, WH, bq, bk, bv, Qb, Kb, Vb);

    attn_kernel<<<2048, 256, 0, stream>>>(Qb, Kb, Vb, maskb, attnH);

    out_gemm<<<512, 256, 0, stream>>>(attnH, WoHp, bo, out);
}